// Round 7
// baseline (318.024 us; speedup 1.0000x reference)
//
#include <hip/hip_runtime.h>
#include <hip/hip_bf16.h>

typedef float  float4v __attribute__((ext_vector_type(4)));
typedef short  short8v __attribute__((ext_vector_type(8)));
typedef short  short4v __attribute__((ext_vector_type(4)));
typedef __bf16 bf16x8  __attribute__((ext_vector_type(8)));
typedef float  f32x4   __attribute__((ext_vector_type(4)));

constexpr int NB = 512, T = 64, DIN = 1024, DOUT = 1024;

// ---- workspace: only folded W needed now (fused path) ----
constexpr size_t WN_BYTES = (size_t)DOUT * DIN * 2;      // 2,097,152

__device__ __forceinline__ short f2bf_rne(float x) {
    return __builtin_bit_cast(short, __float2bfloat16(x));
}
__device__ __forceinline__ short f2bf_trunc(float x) {   // exact for {0,1}
    return (short)(__builtin_bit_cast(unsigned int, x) >> 16);
}
__device__ __forceinline__ void load_lds_16B(const void* g, void* l) {
    __builtin_amdgcn_global_load_lds(
        (const __attribute__((address_space(1))) unsigned int*)g,
        (__attribute__((address_space(3))) unsigned int*)l, 16, 0, 0);
}

// ---- prepass: Wn = bf16(W * gamma/sqrt(rvar)) — 6 MB traffic, ~2 us ----
__global__ void __launch_bounds__(256)
fold_w_kernel(const float* __restrict__ W, const float* __restrict__ gamma,
              const float* __restrict__ rvar, short* __restrict__ Wn) {
    int idx = blockIdx.x * 256 + threadIdx.x;
    int o = idx >> 8;
    float r = gamma[o] / sqrtf(rvar[o]);
    float4v w = ((const float4v*)W)[idx];
    short4v s;
    #pragma unroll
    for (int j = 0; j < 4; j++) s[j] = f2bf_rne(w[j] * r);
    ((short4v*)Wn)[idx] = s;
}

// =====================================================================
// main v7: r6 8-phase shell with A-conversion FUSED (prep_a eliminated).
//
// 256x256 tile, BK=64, 512 thr = 8 waves (2M x 4N), wave-tile 128x64.
// LDS: 2 dbuf x 4 units x 16 KB = 128 KB (A0,A1,B0,B1 per buffer).
//
// Staging of buf[(g+1)&1] during tile g (NO wave reads that buffer
// during g, so no intra-tile WAR — only the end-of-tile barrier
// publishes it):
//   q0: B0(g+1),B1(g+1) via global_load_lds (DMA, oldest in vmem FIFO)
//       + A0(g+1) fp32 reg-loads (4 dwordx4)
//   q1: A1(g+1) fp32 reg-loads
//   q2: convert A0 (trunc, exact for {0,1}) -> ds_write swizzled
//   q3: convert A1 -> ds_write; then vmcnt(0)+lgkmcnt(0)+barrier.
// The compiler's waits for the A-reg uses (q2/q3) drain the older B DMA
// loads for free (FIFO), so the final vmcnt(0) is a no-cost formality;
// loads still span 2-4 phases (T14 issue-early / write-late).
//
// Swizzle (both-sides involution, r0-proven): row r chunk c (16 B bf16)
// at linear chunk c^(r&7); B's DMA source pre-swizzled, A's ds_write
// applies it directly; ds_read XORs the same way. 2 lanes/bank (free).
// =====================================================================
constexpr int BM2 = 256, BN2 = 256, BK2 = 64;
constexpr int NKT = DIN / BK2;                    // 16 K-tiles
constexpr int UNIT = 16384;                       // 128 x 64 bf16
constexpr int DBUF = 4 * UNIT;                    // 64 KB per buffer

__global__ void __launch_bounds__(512, 2)
snn_gemm_if_fused(const float* __restrict__ Afp, // (N*T, DIN) fp32 {0,1}
                  const short* __restrict__ Wn,  // (DOUT, DIN) bf16, folded
                  const float* __restrict__ bias, const float* __restrict__ gamma,
                  const float* __restrict__ beta, const float* __restrict__ rmean,
                  const float* __restrict__ rvar, float* __restrict__ out) {
    __shared__ __align__(16) char sm[2 * DBUF];   // 128 KB; potS aliases
    __shared__ float bstepS[BN2];

    const int tid = threadIdx.x;
    // XCD-chunked swizzle: 512 blocks, 64 contiguous works per XCD;
    // 4 consecutive works share one A panel -> same-XCD L2 reuse of fp32 A.
    const int work = (blockIdx.x & 7) * 64 + (blockIdx.x >> 3);
    const int oB = (work & 3) * BN2;
    const int rg = work >> 2;                     // A rows rg*256.., samples rg*4..

    if (tid < BN2) {
        int o = oB + tid;
        float r = gamma[o] / sqrtf(rvar[o]);
        bstepS[tid] = ((bias[o] - rmean[o]) * r + beta[o]) * (1.0f / 64.0f);
    }
    asm volatile("s_waitcnt vmcnt(0)" ::: "memory");  // retire bstep loads
    __builtin_amdgcn_sched_barrier(0);

    const int lane = tid & 63;
    const int wv   = tid >> 6;                    // 0..7
    const int wr   = wv >> 2;                     // 0..1: M-half (128 rows)
    const int wc   = wv & 3;                      // 0..3: N 64-col band
    const int l15  = lane & 15;
    const int quad = lane >> 4;

    // per-lane ds_read sub-offsets (chunk swizzle c ^= row&7; row&7==lane&7)
    const int D0 = l15 * 128 + ((quad ^ (lane & 7)) * 16);        // ks=0
    const int D1 = l15 * 128 + (((4 + quad) ^ (lane & 7)) * 16);  // ks=1

    // staging geometry: thread covers unit slots tid and tid+512.
    // slot s: row=s>>3, linear chunk s&7 <- global chunk (s&7)^(row&7).
    const int row0 = tid >> 3,         ck0 = (tid & 7) ^ (row0 & 7);
    const int row1 = (512 + tid) >> 3, ck1 = ((512 + tid) & 7) ^ (row1 & 7);
    const int srcOff0 = (row0 * DIN + ck0 * 8) * 2;   // B: bytes (bf16)
    const int srcOff1 = (row1 * DIN + ck1 * 8) * 2;
    const int fo0 = row0 * DIN + ck0 * 8;             // A: float elems
    const int fo1 = row1 * DIN + ck1 * 8;

    const char*  bU[2] = { (const char*)(Wn + (size_t)oB * DIN),
                           (const char*)(Wn + (size_t)(oB + 128) * DIN) };
    const float* aF[2] = { Afp + (size_t)(rg * BM2) * DIN,
                           Afp + (size_t)(rg * BM2 + 128) * DIN };

    auto STAGE_B = [&](const char* uPtr, int ktB, int dstB) {
        load_lds_16B(uPtr + srcOff0 + ktB, sm + dstB + tid * 16);
        load_lds_16B(uPtr + srcOff1 + ktB, sm + dstB + 8192 + tid * 16);
    };
    auto LD8 = [&](const char* p) {
        return __builtin_bit_cast(bf16x8, *(const short8v*)p);
    };
    auto CONV_WRITE = [&](const float4v* a, int dstB) {   // one A unit
        short8v s;
        #pragma unroll
        for (int j = 0; j < 4; j++) { s[j] = f2bf_trunc(a[0][j]);
                                      s[4 + j] = f2bf_trunc(a[1][j]); }
        *(short8v*)(sm + dstB + tid * 16) = s;
        #pragma unroll
        for (int j = 0; j < 4; j++) { s[j] = f2bf_trunc(a[2][j]);
                                      s[4 + j] = f2bf_trunc(a[3][j]); }
        *(short8v*)(sm + dstB + 8192 + tid * 16) = s;
    };

    f32x4 acc[8][4] = {};
    bf16x8 af[4][2], bf0[2][2], bf1[2][2];

    // within-buffer read bases for this wave
    const int aBase = wr * UNIT;
    const int bBase = 2 * UNIT + (wc >> 1) * UNIT + (wc & 1) * 8192;

    // ---- prologue: build buf0 = kt0 ----
    {
        STAGE_B(bU[0], 0, 2 * UNIT);
        STAGE_B(bU[1], 0, 3 * UNIT);
        float4v a0[4], a1[4];
        const float* p00 = aF[0] + fo0;  const float* p01 = aF[0] + fo1;
        a0[0] = *(const float4v*)p00;  a0[1] = *(const float4v*)(p00 + 4);
        a0[2] = *(const float4v*)p01;  a0[3] = *(const float4v*)(p01 + 4);
        const float* p10 = aF[1] + fo0;  const float* p11 = aF[1] + fo1;
        a1[0] = *(const float4v*)p10;  a1[1] = *(const float4v*)(p10 + 4);
        a1[2] = *(const float4v*)p11;  a1[3] = *(const float4v*)(p11 + 4);
        CONV_WRITE(a0, 0);
        CONV_WRITE(a1, UNIT);
        asm volatile("s_waitcnt vmcnt(0) lgkmcnt(0)" ::: "memory");
        __builtin_amdgcn_sched_barrier(0);
        __builtin_amdgcn_s_barrier();
        __builtin_amdgcn_sched_barrier(0);
    }

    #pragma unroll 1
    for (int g = 0; g < NKT; ++g) {
        const int bufB  = (g & 1) ? DBUF : 0;
        const int obufB = (g & 1) ? 0 : DBUF;             // buf[(g+1)&1]
        const char* pA = sm + bufB + aBase;
        const char* pB = sm + bufB + bBase;
        const bool st = (g < NKT - 1);
        const int kE = (g + 1) * BK2;                     // A: float elems
        const int kB = (g + 1) * BK2 * 2;                 // B: bytes
        float4v a0[4], a1[4];

        // ================= q0: quadrant (mh=0, nh=0) =================
        if (st) {
            STAGE_B(bU[0], kB, obufB + 2 * UNIT);         // B0(g+1), oldest
            STAGE_B(bU[1], kB, obufB + 3 * UNIT);         // B1(g+1)
            const float* p0 = aF[0] + fo0 + kE;
            const float* p1 = aF[0] + fo1 + kE;
            a0[0] = *(const float4v*)p0;  a0[1] = *(const float4v*)(p0 + 4);
            a0[2] = *(const float4v*)p1;  a0[3] = *(const float4v*)(p1 + 4);
        }
        __builtin_amdgcn_sched_barrier(0);                // pin issue point
        #pragma unroll
        for (int i = 0; i < 4; i++) {                     // A-mh0: 8 reads
            af[i][0] = LD8(pA + i * 2048 + D0);
            af[i][1] = LD8(pA + i * 2048 + D1);
        }
        #pragma unroll
        for (int j = 0; j < 2; j++) {                     // B-nh0: 4 reads
            bf0[j][0] = LD8(pB + j * 2048 + D0);
            bf0[j][1] = LD8(pB + j * 2048 + D1);
        }
        __builtin_amdgcn_s_barrier();
        __builtin_amdgcn_s_setprio(1);
        #pragma unroll
        for (int mi = 0; mi < 4; mi++)
            #pragma unroll
            for (int ni = 0; ni < 2; ni++)
                #pragma unroll
                for (int ks = 0; ks < 2; ks++)
                    acc[mi][ni] = __builtin_amdgcn_mfma_f32_16x16x32_bf16(
                        af[mi][ks], bf0[ni][ks], acc[mi][ni], 0, 0, 0);
        __builtin_amdgcn_s_setprio(0);
        __builtin_amdgcn_s_barrier();

        // ================= q1: quadrant (mh=0, nh=1) =================
        if (st) {                                         // A1(g+1) reg loads
            const float* p0 = aF[1] + fo0 + kE;
            const float* p1 = aF[1] + fo1 + kE;
            a1[0] = *(const float4v*)p0;  a1[1] = *(const float4v*)(p0 + 4);
            a1[2] = *(const float4v*)p1;  a1[3] = *(const float4v*)(p1 + 4);
        }
        __builtin_amdgcn_sched_barrier(0);
        #pragma unroll
        for (int j = 0; j < 2; j++) {                     // B-nh1: 4 reads
            bf1[j][0] = LD8(pB + 4096 + j * 2048 + D0);
            bf1[j][1] = LD8(pB + 4096 + j * 2048 + D1);
        }
        __builtin_amdgcn_s_barrier();
        __builtin_amdgcn_s_setprio(1);
        #pragma unroll
        for (int mi = 0; mi < 4; mi++)
            #pragma unroll
            for (int ni = 0; ni < 2; ni++)
                #pragma unroll
                for (int ks = 0; ks < 2; ks++)
                    acc[mi][2 + ni] = __builtin_amdgcn_mfma_f32_16x16x32_bf16(
                        af[mi][ks], bf1[ni][ks], acc[mi][2 + ni], 0, 0, 0);
        __builtin_amdgcn_s_setprio(0);
        __builtin_amdgcn_s_barrier();

        // ================= q2: quadrant (mh=1, nh=0) =================
        #pragma unroll
        for (int i = 0; i < 4; i++) {                     // A-mh1: 8 reads
            af[i][0] = LD8(pA + 8192 + i * 2048 + D0);
            af[i][1] = LD8(pA + 8192 + i * 2048 + D1);
        }
        if (st) CONV_WRITE(a0, obufB);                    // A0(g+1) -> LDS
        __builtin_amdgcn_s_barrier();
        __builtin_amdgcn_s_setprio(1);
        #pragma unroll
        for (int mi = 0; mi < 4; mi++)
            #pragma unroll
            for (int ni = 0; ni < 2; ni++)
                #pragma unroll
                for (int ks = 0; ks < 2; ks++)
                    acc[4 + mi][ni] = __builtin_amdgcn_mfma_f32_16x16x32_bf16(
                        af[mi][ks], bf0[ni][ks], acc[4 + mi][ni], 0, 0, 0);
        __builtin_amdgcn_s_setprio(0);
        __builtin_amdgcn_s_barrier();

        // ================= q3: quadrant (mh=1, nh=1) =================
        if (st) CONV_WRITE(a1, obufB + UNIT);             // A1(g+1) -> LDS
        __builtin_amdgcn_s_barrier();
        __builtin_amdgcn_s_setprio(1);
        #pragma unroll
        for (int mi = 0; mi < 4; mi++)
            #pragma unroll
            for (int ni = 0; ni < 2; ni++)
                #pragma unroll
                for (int ks = 0; ks < 2; ks++)
                    acc[4 + mi][2 + ni] = __builtin_amdgcn_mfma_f32_16x16x32_bf16(
                        af[mi][ks], bf1[ni][ks], acc[4 + mi][2 + ni], 0, 0, 0);
        __builtin_amdgcn_s_setprio(0);
        // ---- end-of-tile: publish buf[(g+1)&1] (drains are ~free:
        //      A-reg waits already retired the older B DMA loads) ----
        if (st) {
            asm volatile("s_waitcnt vmcnt(0) lgkmcnt(0)" ::: "memory");
        }
        __builtin_amdgcn_sched_barrier(0);
        __builtin_amdgcn_s_barrier();
        __builtin_amdgcn_sched_barrier(0);
    }

    __syncthreads();                              // full drain; potS aliases

    // ---- epilogue (r2-verified): 2 rounds of 2 samples ----
    float* potS = (float*)sm;                     // 128 x 256 fp32 = 128 KB
    #pragma unroll 1
    for (int rd = 0; rd < 2; ++rd) {
        if (wr == rd) {                           // this wave's 128 rows
            #pragma unroll
            for (int mi = 0; mi < 8; mi++)
                #pragma unroll
                for (int ni = 0; ni < 4; ni++)
                    #pragma unroll
                    for (int r = 0; r < 4; r++) {
                        int rowl = mi * 16 + quad * 4 + r;
                        int col  = (wc * 64 + ni * 16 + l15) ^ (quad << 3);
                        potS[rowl * BN2 + col] = acc[mi][ni][r];
                    }
        }
        __syncthreads();
        {
            int sl = tid >> 8;                    // 0..1: sample within round
            int c  = tid & 255;
            int n  = rg * 4 + rd * 2 + sl;
            float pot = 0.f, cnt = 0.f;
            const float bst = bstepS[c];
            float* so = out + (size_t)n * T * DOUT + oB + c;
            for (int tt = 0; tt < T; tt++) {
                pot += potS[(sl * 64 + tt) * BN2 + (c ^ (((tt >> 2) & 3) << 3))] + bst;
                float spk = (pot >= 1.0f) ? 1.0f : 0.0f;
                pot -= spk;
                cnt += spk;
                __builtin_nontemporal_store(spk, so + (size_t)tt * DOUT);
            }
            __builtin_nontemporal_store(
                cnt, out + (size_t)NB * T * DOUT + (size_t)n * DOUT + oB + c);
        }
        __syncthreads();
    }
}

// ===================== fallback (no workspace): proven path =====================

constexpr int BM = 128, BN = 128, BK = 64;
constexpr int LDA_F = 72;
constexpr int A_BYTES_F = BM * LDA_F * 2;
constexpr int SMEM_F = A_BYTES_F + BN * BK * 2;

__global__ void __launch_bounds__(256)
snn_gemm_if(const float* __restrict__ A, const float* __restrict__ W,
            const float* __restrict__ bias, const float* __restrict__ gamma,
            const float* __restrict__ beta, const float* __restrict__ rmean,
            const float* __restrict__ rvar, float* __restrict__ out) {
    __shared__ __align__(16) char smem[SMEM_F];
    __shared__ float ratioS[BN];
    __shared__ float bstepS[BN];
    short* AsS  = (short*)smem;
    short* BsS  = (short*)(smem + A_BYTES_F);
    float* potS = (float*)smem;

    const int tid   = threadIdx.x;
    const int by    = blockIdx.y;
    const int oBase = blockIdx.x * BN;

    if (tid < BN) {
        int o = oBase + tid;
        float r = gamma[o] / sqrtf(rvar[o]);
        ratioS[tid] = r;
        bstepS[tid] = ((bias[o] - rmean[o]) * r + beta[o]) * (1.0f / 64.0f);
    }
    __syncthreads();

    const int lane = tid & 63;
    const int wv   = tid >> 6;
    const int wr   = wv & 1;
    const int wc   = wv >> 1;
    const int l15  = lane & 15;
    const int quad = lane >> 4;

    f32x4 acc[4][4] = {};
    const float* Ab = A + (size_t)by * BM * DIN;

    for (int kb = 0; kb < DIN; kb += BK) {
        float4v av[4][2];
        #pragma unroll
        for (int i = 0; i < 4; i++) {
            int g = i * 256 + tid;
            int r = g >> 3, k8 = g & 7;
            const float4v* p = (const float4v*)(Ab + (size_t)r * DIN + kb + k8 * 8);
            av[i][0] = p[0];
            av[i][1] = p[1];
        }
        float4v bv[4][2];
        #pragma unroll
        for (int i = 0; i < 4; i++) {
            int slot = i * 256 + tid;
            int r = slot >> 3, k8 = (slot & 7) ^ (r & 7);
            const float4v* p = (const float4v*)(W + (size_t)(oBase + r) * DIN + kb + k8 * 8);
            bv[i][0] = p[0];
            bv[i][1] = p[1];
        }
        __syncthreads();

        #pragma unroll
        for (int i = 0; i < 4; i++) {
            int slot = i * 256 + tid;
            int r = slot >> 3;
            float rt = ratioS[r];
            short8v s;
            #pragma unroll
            for (int j = 0; j < 4; j++) {
                s[j]     = f2bf_rne(bv[i][0][j] * rt);
                s[j + 4] = f2bf_rne(bv[i][1][j] * rt);
            }
            *(short8v*)(BsS + (size_t)slot * 8) = s;
        }
        #pragma unroll
        for (int i = 0; i < 4; i++) {
            int g = i * 256 + tid;
            int r = g >> 3, k8 = g & 7;
            short8v s;
            #pragma unroll
            for (int j = 0; j < 4; j++) {
                s[j]     = f2bf_trunc(av[i][0][j]);
                s[j + 4] = f2bf_trunc(av[i][1][j]);
            }
            *(short8v*)(&AsS[r * LDA_F + k8 * 8]) = s;
        }
        __syncthreads();

        #pragma unroll
        for (int ks = 0; ks < 2; ks++) {
            bf16x8 af[4], bfv[4];
            #pragma unroll
            for (int mi = 0; mi < 4; mi++)
                af[mi] = __builtin_bit_cast(bf16x8,
                    *(const short8v*)(&AsS[(wr * 64 + mi * 16 + l15) * LDA_F + ks * 32 + quad * 8]));
            #pragma unroll
            for (int ni = 0; ni < 4; ni++) {
                int row  = wc * 64 + ni * 16 + l15;
                int slot = row * 8 + ((ks * 4 + quad) ^ (l15 & 7));
                bfv[ni] = __builtin_bit_cast(bf16x8, *(const short8v*)(BsS + (size_t)slot * 8));
            }
            #pragma unroll
            for (int mi = 0; mi < 4; mi++)
                #pragma unroll
                for (int ni = 0; ni < 4; ni++)
                    acc[mi][ni] = __builtin_amdgcn_mfma_f32_16x16x32_bf16(
                        af[mi], bfv[ni], acc[mi][ni], 0, 0, 0);
        }
    }

    __syncthreads();

    #pragma unroll 1
    for (int s = 0; s < 2; s++) {
        if (wr == s) {
            #pragma unroll
            for (int mi = 0; mi < 4; mi++)
                #pragma unroll
                for (int ni = 0; ni < 4; ni++)
                    #pragma unroll
                    for (int r = 0; r < 4; r++)
                        potS[(mi * 16 + quad * 4 + r) * BN + wc * 64 + ni * 16 + l15] =
                            acc[mi][ni][r];
        }
        __syncthreads();
        if (tid < BN) {
            int n = by * 2 + s;
            float pot = 0.f, cnt = 0.f;
            const float bst = bstepS[tid];
            float* so = out + (size_t)n * T * DOUT + oBase + tid;
            for (int t = 0; t < T; t++) {
                pot += potS[t * BN + tid] + bst;
                float spk = (pot >= 1.0f) ? 1.0f : 0.0f;
                pot -= spk;
                cnt += spk;
                so[(size_t)t * DOUT] = spk;
            }
            out[(size_t)NB * T * DOUT + (size_t)n * DOUT + oBase + tid] = cnt;
        }
        __syncthreads();
    }
}

extern "C" void kernel_launch(void* const* d_in, const int* in_sizes, int n_in,
                              void* d_out, int out_size, void* d_ws, size_t ws_size,
                              hipStream_t stream) {
    const float* A     = (const float*)d_in[0];
    // d_in[1] (input_features_sc) feeds only the un-returned ANN path — dead.
    const float* W     = (const float*)d_in[2];
    const float* bias  = (const float*)d_in[3];
    const float* gamma = (const float*)d_in[4];
    const float* beta  = (const float*)d_in[5];
    const float* rmean = (const float*)d_in[6];
    const float* rvar  = (const float*)d_in[7];
    float* out = (float*)d_out;

    if (d_ws != nullptr && ws_size >= WN_BYTES) {
        short* Wn = (short*)d_ws;
        fold_w_kernel<<<DOUT * DIN / 4 / 256, 256, 0, stream>>>(W, gamma, rvar, Wn);
        snn_gemm_if_fused<<<dim3(512), 512, 0, stream>>>(A, Wn, bias, gamma,
                                                         beta, rmean, rvar, out);
    } else {
        dim3 grid(DOUT / BN, NB / 2);
        snn_gemm_if<<<grid, 256, 0, stream>>>(A, W, bias, gamma, beta,
                                              rmean, rvar, out);
    }
}

// Round 8
// 313.684 us; speedup vs baseline: 1.0138x; 1.0138x over previous
//
#include <hip/hip_runtime.h>
#include <hip/hip_bf16.h>

typedef float  float4v __attribute__((ext_vector_type(4)));
typedef short  short8v __attribute__((ext_vector_type(8)));
typedef short  short4v __attribute__((ext_vector_type(4)));
typedef __bf16 bf16x8  __attribute__((ext_vector_type(8)));
typedef float  f32x4   __attribute__((ext_vector_type(4)));

constexpr int NB = 512, T = 64, DIN = 1024, DOUT = 1024;

// ---- workspace layout (bf16-DMA path) ----
constexpr size_t ABF_BYTES = (size_t)NB * T * DIN * 2;   // 67,108,864
constexpr size_t WN_BYTES  = (size_t)DOUT * DIN * 2;     // 2,097,152
constexpr size_t WS_BF16   = ABF_BYTES + WN_BYTES;       // ~69 MB

__device__ __forceinline__ short f2bf_rne(float x) {
    return __builtin_bit_cast(short, __float2bfloat16(x));
}
__device__ __forceinline__ short f2bf_trunc(float x) {   // exact for {0,1}
    return (short)(__builtin_bit_cast(unsigned int, x) >> 16);
}
__device__ __forceinline__ void load_lds_16B(const void* g, void* l) {
    __builtin_amdgcn_global_load_lds(
        (const __attribute__((address_space(1))) unsigned int*)g,
        (__attribute__((address_space(3))) unsigned int*)l, 16, 0, 0);
}

// ---- fused prepass: A fp32{0,1} -> bf16 (trunc) AND Wn = bf16(W*ratio)
// r8: A loads CACHED (not nontemporal) -- A likely L3-resident (134 MB
// < 256 MB L3, written by harness); nt loads were bypassing it. Grid-
// stride 2048-block A-part per G11. Both A fp32 (134) + Abf (67) fit L3.
constexpr int PREP_A_BLOCKS = 2048;
constexpr int PREP_W_BLOCKS = DOUT * DIN / 4 / 256;      // 1024
constexpr int PREP_A_STRIDE = PREP_A_BLOCKS * 256;       // 8-elem groups/iter
constexpr int PREP_A_ITERS  = (NB * T * DIN / 8) / PREP_A_STRIDE;  // 8

__global__ void __launch_bounds__(256)
prep_fused(const float* __restrict__ A, short* __restrict__ Abf,
           const float* __restrict__ W, const float* __restrict__ gamma,
           const float* __restrict__ rvar, short* __restrict__ Wn) {
    const int b = blockIdx.x;
    if (b < PREP_A_BLOCKS) {
        int base = b * 256 + threadIdx.x;
        #pragma unroll
        for (int it = 0; it < PREP_A_ITERS; ++it) {
            int idx = it * PREP_A_STRIDE + base;         // 8-elem group
            const float4v* p = (const float4v*)A + (size_t)idx * 2;
            float4v v0 = p[0];                           // cached: L3 may serve
            float4v v1 = p[1];
            short8v s;
            #pragma unroll
            for (int j = 0; j < 4; j++) {
                s[j]     = f2bf_trunc(v0[j]);
                s[j + 4] = f2bf_trunc(v1[j]);
            }
            *((short8v*)Abf + idx) = s;                  // cached: re-read soon
        }
    } else {
        int idx = (b - PREP_A_BLOCKS) * 256 + threadIdx.x;  // float4 group
        int o = idx >> 8;
        float r = gamma[o] / sqrtf(rvar[o]);
        float4v w = ((const float4v*)W)[idx];
        short4v s;
        #pragma unroll
        for (int j = 0; j < 4; j++) s[j] = f2bf_rne(w[j] * r);
        ((short4v*)Wn)[idx] = s;
    }
}

// standalone fold (used by the ws-small fallback path only)
__global__ void __launch_bounds__(256)
fold_w_kernel(const float* __restrict__ W, const float* __restrict__ gamma,
              const float* __restrict__ rvar, short* __restrict__ Wn) {
    int idx = blockIdx.x * 256 + threadIdx.x;
    int o = idx >> 8;
    float r = gamma[o] / sqrtf(rvar[o]);
    float4v w = ((const float4v*)W)[idx];
    short4v s;
    #pragma unroll
    for (int j = 0; j < 4; j++) s[j] = f2bf_rne(w[j] * r);
    ((short4v*)Wn)[idx] = s;
}

// =====================================================================
// main (r6-proven, 85 us): 256x256 tile, BK=64, 512 thr = 8 waves
// (2M x 4N), wave-tile 128x64, acc[8][4]. 4 fine phases per K-tile,
// unit-ordered staging, counted vmcnt(4) once per K-tile.
// See r6 notes: this structure measured 85 us / MfmaUtil 32%.
// =====================================================================
constexpr int BM2 = 256, BN2 = 256, BK2 = 64;
constexpr int NKT = DIN / BK2;                    // 16 K-tiles
constexpr int UNIT = 16384;                       // 128 x 64 bf16
constexpr int DBUF = 4 * UNIT;                    // 64 KB per buffer

__global__ void __launch_bounds__(512, 2)
snn_gemm_if_8ph(const short* __restrict__ Abf,  // (N*T, DIN) bf16 {0,1}
                const short* __restrict__ Wn,   // (DOUT, DIN) bf16, folded
                const float* __restrict__ bias, const float* __restrict__ gamma,
                const float* __restrict__ beta, const float* __restrict__ rmean,
                const float* __restrict__ rvar, float* __restrict__ out) {
    __shared__ __align__(16) char sm[2 * DBUF];   // 128 KB; potS aliases
    __shared__ float bstepS[BN2];

    const int tid = threadIdx.x;
    // XCD-chunked swizzle: 512 blocks, 64 contiguous works per XCD;
    // 4 consecutive works share an A panel.
    const int work = (blockIdx.x & 7) * 64 + (blockIdx.x >> 3);
    const int oB = (work & 3) * BN2;
    const int rg = work >> 2;                     // A rows rg*256.., samples rg*4..

    if (tid < BN2) {
        int o = oB + tid;
        float r = gamma[o] / sqrtf(rvar[o]);
        bstepS[tid] = ((bias[o] - rmean[o]) * r + beta[o]) * (1.0f / 64.0f);
    }
    // retire bstep loads so vmcnt accounting below is exact
    asm volatile("s_waitcnt vmcnt(0)" ::: "memory");
    __builtin_amdgcn_sched_barrier(0);

    const int lane = tid & 63;
    const int wv   = tid >> 6;                    // 0..7
    const int wr   = wv >> 2;                     // 0..1: M-half (128 rows)
    const int wc   = wv & 3;                      // 0..3: N 64-col band
    const int l15  = lane & 15;
    const int quad = lane >> 4;

    // per-lane ds_read sub-offsets (chunk swizzle c ^= row&7; row&7==lane&7)
    const int D0 = l15 * 128 + ((quad ^ (lane & 7)) * 16);        // ks=0
    const int D1 = l15 * 128 + (((4 + quad) ^ (lane & 7)) * 16);  // ks=1

    // staging: thread covers unit slots tid and tid+512.
    // slot s: row=s>>3, linear chunk s&7 <- global chunk (s&7)^(row&7).
    const int row0 = tid >> 3,         ck0 = (tid & 7) ^ (row0 & 7);
    const int row1 = (512 + tid) >> 3, ck1 = ((512 + tid) & 7) ^ (row1 & 7);
    const int srcOff0 = (row0 * DIN + ck0 * 8) * 2;   // bytes
    const int srcOff1 = (row1 * DIN + ck1 * 8) * 2;

    const char* aU[2] = { (const char*)(Abf + (size_t)rg * BM2 * DIN),
                          (const char*)(Abf + (size_t)(rg * BM2 + 128) * DIN) };
    const char* bU[2] = { (const char*)(Wn + (size_t)oB * DIN),
                          (const char*)(Wn + (size_t)(oB + 128) * DIN) };

    auto STAGE = [&](const char* uPtr, int ktB, int dstB) {
        load_lds_16B(uPtr + srcOff0 + ktB, sm + dstB + tid * 16);
        load_lds_16B(uPtr + srcOff1 + ktB, sm + dstB + 8192 + tid * 16);
    };
    auto LD8 = [&](const char* p) {
        return __builtin_bit_cast(bf16x8, *(const short8v*)p);
    };

    f32x4 acc[8][4] = {};
    bf16x8 af[4][2], bf0[2][2], bf1[2][2];

    // within-buffer read bases for this wave
    const int aBase = wr * UNIT;                          // unit A{wr}
    const int bBase = 2 * UNIT + (wc >> 1) * UNIT + (wc & 1) * 8192;

    // ---- prologue: kt0 (buf0) then kt1 (buf1); land kt0 ----
    STAGE(aU[0], 0, 0);           STAGE(aU[1], 0, UNIT);
    STAGE(bU[0], 0, 2 * UNIT);    STAGE(bU[1], 0, 3 * UNIT);
    STAGE(aU[0], 128, DBUF);      STAGE(aU[1], 128, DBUF + UNIT);
    STAGE(bU[0], 128, DBUF + 2 * UNIT);
    STAGE(bU[1], 128, DBUF + 3 * UNIT);
    asm volatile("s_waitcnt vmcnt(8)" ::: "memory");      // kt0's 8 loads done
    __builtin_amdgcn_sched_barrier(0);
    __builtin_amdgcn_s_barrier();
    __builtin_amdgcn_sched_barrier(0);

    #pragma unroll 1
    for (int g = 0; g < NKT; ++g) {
        const int bufB  = (g & 1) ? DBUF : 0;
        const int obufB = (g & 1) ? 0 : DBUF;             // buf[(g+1)&1]
        const int ktB1  = (g + 1) * 128;                  // A-stage K offset
        const int ktB2  = (g + 2) * 128;                  // B-stage K offset
        const char* pA = sm + bufB + aBase;
        const char* pB = sm + bufB + bBase;
        const bool stA = (g >= 1) && (g <= NKT - 2);      // kt g+1 A units
        const bool stB = (g <= NKT - 3);                  // kt g+2 B units

        // ================= q0: quadrant (mh=0, nh=0) =================
        #pragma unroll
        for (int i = 0; i < 4; i++) {                     // A-mh0: 8 reads
            af[i][0] = LD8(pA + i * 2048 + D0);
            af[i][1] = LD8(pA + i * 2048 + D1);
        }
        #pragma unroll
        for (int j = 0; j < 2; j++) {                     // B-nh0: 4 reads
            bf0[j][0] = LD8(pB + j * 2048 + D0);
            bf0[j][1] = LD8(pB + j * 2048 + D1);
        }
        if (stA) STAGE(aU[0], ktB1, obufB);               // A0(g+1)
        __builtin_amdgcn_s_barrier();
        __builtin_amdgcn_s_setprio(1);
        #pragma unroll
        for (int mi = 0; mi < 4; mi++)
            #pragma unroll
            for (int ni = 0; ni < 2; ni++)
                #pragma unroll
                for (int ks = 0; ks < 2; ks++)
                    acc[mi][ni] = __builtin_amdgcn_mfma_f32_16x16x32_bf16(
                        af[mi][ks], bf0[ni][ks], acc[mi][ni], 0, 0, 0);
        __builtin_amdgcn_s_setprio(0);
        __builtin_amdgcn_s_barrier();

        // ================= q1: quadrant (mh=0, nh=1) =================
        #pragma unroll
        for (int j = 0; j < 2; j++) {                     // B-nh1: 4 reads
            bf1[j][0] = LD8(pB + 4096 + j * 2048 + D0);
            bf1[j][1] = LD8(pB + 4096 + j * 2048 + D1);
        }
        if (stA) STAGE(aU[1], ktB1, obufB + UNIT);        // A1(g+1)
        __builtin_amdgcn_s_barrier();
        __builtin_amdgcn_s_setprio(1);
        #pragma unroll
        for (int mi = 0; mi < 4; mi++)
            #pragma unroll
            for (int ni = 0; ni < 2; ni++)
                #pragma unroll
                for (int ks = 0; ks < 2; ks++)
                    acc[mi][2 + ni] = __builtin_amdgcn_mfma_f32_16x16x32_bf16(
                        af[mi][ks], bf1[ni][ks], acc[mi][2 + ni], 0, 0, 0);
        __builtin_amdgcn_s_setprio(0);
        __builtin_amdgcn_s_barrier();

        // ================= q2: quadrant (mh=1, nh=0) =================
        #pragma unroll
        for (int i = 0; i < 4; i++) {                     // A-mh1: 8 reads
            af[i][0] = LD8(pA + 8192 + i * 2048 + D0);
            af[i][1] = LD8(pA + 8192 + i * 2048 + D1);
        }
        if (stB) STAGE(bU[0], ktB2, bufB + 2 * UNIT);     // B0(g+2)
        __builtin_amdgcn_s_barrier();
        __builtin_amdgcn_s_setprio(1);
        #pragma unroll
        for (int mi = 0; mi < 4; mi++)
            #pragma unroll
            for (int ni = 0; ni < 2; ni++)
                #pragma unroll
                for (int ks = 0; ks < 2; ks++)
                    acc[4 + mi][ni] = __builtin_amdgcn_mfma_f32_16x16x32_bf16(
                        af[mi][ks], bf0[ni][ks], acc[4 + mi][ni], 0, 0, 0);
        __builtin_amdgcn_s_setprio(0);
        __builtin_amdgcn_s_barrier();

        // ================= q3: quadrant (mh=1, nh=1) =================
        if (stB) STAGE(bU[1], ktB2, bufB + 3 * UNIT);     // B1(g+2)
        __builtin_amdgcn_s_barrier();
        __builtin_amdgcn_s_setprio(1);
        #pragma unroll
        for (int mi = 0; mi < 4; mi++)
            #pragma unroll
            for (int ni = 0; ni < 2; ni++)
                #pragma unroll
                for (int ks = 0; ks < 2; ks++)
                    acc[4 + mi][2 + ni] = __builtin_amdgcn_mfma_f32_16x16x32_bf16(
                        af[mi][ks], bf1[ni][ks], acc[4 + mi][2 + ni], 0, 0, 0);
        __builtin_amdgcn_s_setprio(0);
        // ---- once-per-K-tile checkpoint: kt g+1 fully landed ----
        if (g <= NKT - 3) {
            asm volatile("s_waitcnt vmcnt(4)" ::: "memory");
        } else if (g == NKT - 2) {
            asm volatile("s_waitcnt vmcnt(0)" ::: "memory");
        }
        __builtin_amdgcn_sched_barrier(0);
        __builtin_amdgcn_s_barrier();
        __builtin_amdgcn_sched_barrier(0);
    }

    __syncthreads();                              // full drain; potS aliases

    // ---- epilogue (r2-verified): 2 rounds of 2 samples ----
    float* potS = (float*)sm;                     // 128 x 256 fp32 = 128 KB
    #pragma unroll 1
    for (int rd = 0; rd < 2; ++rd) {
        if (wr == rd) {                           // this wave's 128 rows
            #pragma unroll
            for (int mi = 0; mi < 8; mi++)
                #pragma unroll
                for (int ni = 0; ni < 4; ni++)
                    #pragma unroll
                    for (int r = 0; r < 4; r++) {
                        int rowl = mi * 16 + quad * 4 + r;
                        int col  = (wc * 64 + ni * 16 + l15) ^ (quad << 3);
                        potS[rowl * BN2 + col] = acc[mi][ni][r];
                    }
        }
        __syncthreads();
        {
            int sl = tid >> 8;                    // 0..1: sample within round
            int c  = tid & 255;
            int n  = rg * 4 + rd * 2 + sl;
            float pot = 0.f, cnt = 0.f;
            const float bst = bstepS[c];
            float* so = out + (size_t)n * T * DOUT + oB + c;
            #pragma unroll 8
            for (int tt = 0; tt < T; tt++) {
                pot += potS[(sl * 64 + tt) * BN2 + (c ^ (((tt >> 2) & 3) << 3))] + bst;
                float spk = (pot >= 1.0f) ? 1.0f : 0.0f;
                pot -= spk;
                cnt += spk;
                __builtin_nontemporal_store(spk, so + (size_t)tt * DOUT);
            }
            __builtin_nontemporal_store(
                cnt, out + (size_t)NB * T * DOUT + (size_t)n * DOUT + oB + c);
        }
        __syncthreads();
    }
}

// ===================== fallback (round-2 proven path) =====================

constexpr int BM = 128, BN = 128, BK = 64;
constexpr int LDA_F = 72;
constexpr int A_BYTES_F = BM * LDA_F * 2;
constexpr int SMEM_F = A_BYTES_F + BN * BK * 2;

template <bool PREFOLD>
__global__ void __launch_bounds__(256)
snn_gemm_if(const float* __restrict__ A, const float* __restrict__ W,
            const short* __restrict__ Wn,
            const float* __restrict__ bias, const float* __restrict__ gamma,
            const float* __restrict__ beta, const float* __restrict__ rmean,
            const float* __restrict__ rvar, float* __restrict__ out) {
    __shared__ __align__(16) char smem[SMEM_F];
    __shared__ float ratioS[BN];
    __shared__ float bstepS[BN];
    short* AsS  = (short*)smem;
    short* BsS  = (short*)(smem + A_BYTES_F);
    float* potS = (float*)smem;

    const int tid   = threadIdx.x;
    const int by    = blockIdx.y;
    const int oBase = blockIdx.x * BN;

    if (tid < BN) {
        int o = oBase + tid;
        float r = gamma[o] / sqrtf(rvar[o]);
        ratioS[tid] = r;
        bstepS[tid] = ((bias[o] - rmean[o]) * r + beta[o]) * (1.0f / 64.0f);
    }
    __syncthreads();

    const int lane = tid & 63;
    const int wv   = tid >> 6;
    const int wr   = wv & 1;
    const int wc   = wv >> 1;
    const int l15  = lane & 15;
    const int quad = lane >> 4;

    f32x4 acc[4][4] = {};
    const float* Ab = A + (size_t)by * BM * DIN;

    for (int kb = 0; kb < DIN; kb += BK) {
        float4v av[4][2];
        #pragma unroll
        for (int i = 0; i < 4; i++) {
            int g = i * 256 + tid;
            int r = g >> 3, k8 = g & 7;
            const float4v* p = (const float4v*)(Ab + (size_t)r * DIN + kb + k8 * 8);
            av[i][0] = p[0];
            av[i][1] = p[1];
        }
        float4v bv[4][2];
        if constexpr (!PREFOLD) {
            #pragma unroll
            for (int i = 0; i < 4; i++) {
                int slot = i * 256 + tid;
                int r = slot >> 3, k8 = (slot & 7) ^ (r & 7);
                const float4v* p = (const float4v*)(W + (size_t)(oBase + r) * DIN + kb + k8 * 8);
                bv[i][0] = p[0];
                bv[i][1] = p[1];
            }
        }
        __syncthreads();

        if constexpr (PREFOLD) {
            #pragma unroll
            for (int i = 0; i < 4; i++) {
                int slot = i * 256 + tid;
                int r = slot >> 3, k8 = (slot & 7) ^ (r & 7);
                load_lds_16B(Wn + (size_t)(oBase + r) * DIN + kb + k8 * 8,
                             BsS + (size_t)slot * 8);
            }
        } else {
            #pragma unroll
            for (int i = 0; i < 4; i++) {
                int slot = i * 256 + tid;
                int r = slot >> 3;
                float rt = ratioS[r];
                short8v s;
                #pragma unroll
                for (int j = 0; j < 4; j++) {
                    s[j]     = f2bf_rne(bv[i][0][j] * rt);
                    s[j + 4] = f2bf_rne(bv[i][1][j] * rt);
                }
                *(short8v*)(BsS + (size_t)slot * 8) = s;
            }
        }
        #pragma unroll
        for (int i = 0; i < 4; i++) {
            int g = i * 256 + tid;
            int r = g >> 3, k8 = g & 7;
            short8v s;
            #pragma unroll
            for (int j = 0; j < 4; j++) {
                s[j]     = f2bf_trunc(av[i][0][j]);
                s[j + 4] = f2bf_trunc(av[i][1][j]);
            }
            *(short8v*)(&AsS[r * LDA_F + k8 * 8]) = s;
        }
        __syncthreads();

        #pragma unroll
        for (int ks = 0; ks < 2; ks++) {
            bf16x8 af[4], bfv[4];
            #pragma unroll
            for (int mi = 0; mi < 4; mi++)
                af[mi] = __builtin_bit_cast(bf16x8,
                    *(const short8v*)(&AsS[(wr * 64 + mi * 16 + l15) * LDA_F + ks * 32 + quad * 8]));
            #pragma unroll
            for (int ni = 0; ni < 4; ni++) {
                int row  = wc * 64 + ni * 16 + l15;
                int slot = row * 8 + ((ks * 4 + quad) ^ (l15 & 7));
                bfv[ni] = __builtin_bit_cast(bf16x8, *(const short8v*)(BsS + (size_t)slot * 8));
            }
            #pragma unroll
            for (int mi = 0; mi < 4; mi++)
                #pragma unroll
                for (int ni = 0; ni < 4; ni++)
                    acc[mi][ni] = __builtin_amdgcn_mfma_f32_16x16x32_bf16(
                        af[mi], bfv[ni], acc[mi][ni], 0, 0, 0);
        }
    }

    __syncthreads();

    #pragma unroll 1
    for (int s = 0; s < 2; s++) {
        if (wr == s) {
            #pragma unroll
            for (int mi = 0; mi < 4; mi++)
                #pragma unroll
                for (int ni = 0; ni < 4; ni++)
                    #pragma unroll
                    for (int r = 0; r < 4; r++)
                        potS[(mi * 16 + quad * 4 + r) * BN + wc * 64 + ni * 16 + l15] =
                            acc[mi][ni][r];
        }
        __syncthreads();
        if (tid < BN) {
            int n = by * 2 + s;
            float pot = 0.f, cnt = 0.f;
            const float bst = bstepS[tid];
            float* so = out + (size_t)n * T * DOUT + oBase + tid;
            #pragma unroll 8
            for (int t = 0; t < T; t++) {
                pot += potS[t * BN + tid] + bst;
                float spk = (pot >= 1.0f) ? 1.0f : 0.0f;
                pot -= spk;
                cnt += spk;
                so[(size_t)t * DOUT] = spk;
            }
            out[(size_t)NB * T * DOUT + (size_t)n * DOUT + oBase + tid] = cnt;
        }
        __syncthreads();
    }
}

extern "C" void kernel_launch(void* const* d_in, const int* in_sizes, int n_in,
                              void* d_out, int out_size, void* d_ws, size_t ws_size,
                              hipStream_t stream) {
    const float* A     = (const float*)d_in[0];
    // d_in[1] (input_features_sc) feeds only the un-returned ANN path — dead.
    const float* W     = (const float*)d_in[2];
    const float* bias  = (const float*)d_in[3];
    const float* gamma = (const float*)d_in[4];
    const float* beta  = (const float*)d_in[5];
    const float* rmean = (const float*)d_in[6];
    const float* rvar  = (const float*)d_in[7];
    float* out = (float*)d_out;

    if (d_ws != nullptr && ws_size >= WS_BF16) {
        short* Abf = (short*)d_ws;
        short* Wn  = (short*)((char*)d_ws + ABF_BYTES);
        prep_fused<<<PREP_A_BLOCKS + PREP_W_BLOCKS, 256, 0, stream>>>(
            A, Abf, W, gamma, rvar, Wn);
        snn_gemm_if_8ph<<<dim3(512), 512, 0, stream>>>(Abf, Wn, bias, gamma,
                                                       beta, rmean, rvar, out);
    } else if (d_ws != nullptr && ws_size >= WN_BYTES) {
        short* Wn = (short*)d_ws;
        fold_w_kernel<<<DOUT * DIN / 4 / 256, 256, 0, stream>>>(W, gamma, rvar, Wn);
        dim3 grid(DOUT / BN, NB / 2);
        snn_gemm_if<true><<<grid, 256, 0, stream>>>(A, W, Wn, bias, gamma, beta,
                                                    rmean, rvar, out);
    } else {
        dim3 grid(DOUT / BN, NB / 2);
        snn_gemm_if<false><<<grid, 256, 0, stream>>>(A, W, nullptr, bias, gamma, beta,
                                                     rmean, rvar, out);
    }
}

// Round 9
// 300.456 us; speedup vs baseline: 1.0585x; 1.0440x over previous
//
#include <hip/hip_runtime.h>
#include <hip/hip_bf16.h>

typedef float  float4v __attribute__((ext_vector_type(4)));
typedef short  short8v __attribute__((ext_vector_type(8)));
typedef short  short4v __attribute__((ext_vector_type(4)));
typedef __bf16 bf16x8  __attribute__((ext_vector_type(8)));
typedef float  f32x4   __attribute__((ext_vector_type(4)));

constexpr int NB = 512, T = 64, DIN = 1024, DOUT = 1024;

// ---- workspace layout (bf16-DMA path) ----
constexpr size_t ABF_BYTES = (size_t)NB * T * DIN * 2;   // 67,108,864
constexpr size_t WN_BYTES  = (size_t)DOUT * DIN * 2;     // 2,097,152
constexpr size_t WS_BF16   = ABF_BYTES + WN_BYTES;       // ~69 MB

__device__ __forceinline__ short f2bf_rne(float x) {
    return __builtin_bit_cast(short, __float2bfloat16(x));
}
__device__ __forceinline__ short f2bf_trunc(float x) {   // exact for {0,1}
    return (short)(__builtin_bit_cast(unsigned int, x) >> 16);
}
__device__ __forceinline__ void load_lds_16B(const void* g, void* l) {
    __builtin_amdgcn_global_load_lds(
        (const __attribute__((address_space(1))) unsigned int*)g,
        (__attribute__((address_space(3))) unsigned int*)l, 16, 0, 0);
}

// ---- fused prepass: A fp32{0,1} -> bf16 (trunc, exact) AND Wn = bf16(W*ratio)
// (r6-proven form. r8's cached/grid-stride variant measured null; prep is at
// its mixed-R/W streaming floor ~41-44 us vs 32 ideal.)
constexpr int PREP_A_BLOCKS = NB * T * DIN / 8 / 256;    // 16384
constexpr int PREP_W_BLOCKS = DOUT * DIN / 4 / 256;      // 1024

__global__ void __launch_bounds__(256)
prep_fused(const float* __restrict__ A, short* __restrict__ Abf,
           const float* __restrict__ W, const float* __restrict__ gamma,
           const float* __restrict__ rvar, short* __restrict__ Wn) {
    const int b = blockIdx.x;
    if (b < PREP_A_BLOCKS) {
        int idx = b * 256 + threadIdx.x;                 // 8-elem group
        const float4v* p = (const float4v*)A + (size_t)idx * 2;
        float4v v0 = __builtin_nontemporal_load(p);
        float4v v1 = __builtin_nontemporal_load(p + 1);
        short8v s;
        #pragma unroll
        for (int j = 0; j < 4; j++) {
            s[j]     = f2bf_trunc(v0[j]);
            s[j + 4] = f2bf_trunc(v1[j]);
        }
        *((short8v*)Abf + idx) = s;                      // cached: re-read soon
    } else {
        int idx = (b - PREP_A_BLOCKS) * 256 + threadIdx.x;  // float4 group
        int o = idx >> 8;
        float r = gamma[o] / sqrtf(rvar[o]);
        float4v w = ((const float4v*)W)[idx];
        short4v s;
        #pragma unroll
        for (int j = 0; j < 4; j++) s[j] = f2bf_rne(w[j] * r);
        ((short4v*)Wn)[idx] = s;
    }
}

// standalone fold (used by the ws-small fallback path only)
__global__ void __launch_bounds__(256)
fold_w_kernel(const float* __restrict__ W, const float* __restrict__ gamma,
              const float* __restrict__ rvar, short* __restrict__ Wn) {
    int idx = blockIdx.x * 256 + threadIdx.x;
    int o = idx >> 8;
    float r = gamma[o] / sqrtf(rvar[o]);
    float4v w = ((const float4v*)W)[idx];
    short4v s;
    #pragma unroll
    for (int j = 0; j < 4; j++) s[j] = f2bf_rne(w[j] * r);
    ((short4v*)Wn)[idx] = s;
}

// =====================================================================
// main (r6-proven, best measured: 85 us, MfmaUtil 32%, total 300.0):
// 256x256 tile, BK=64, 512 thr = 8 waves (2M x 4N), wave-tile 128x64,
// acc[8][4]. 4 fine phases per K-tile, unit-ordered staging, counted
// vmcnt(4) once per K-tile. NOTE (r8 lesson): do NOT add unroll
// pragmas to the epilogue scan — unroll 8 regressed the gemm 85->95.
// =====================================================================
constexpr int BM2 = 256, BN2 = 256, BK2 = 64;
constexpr int NKT = DIN / BK2;                    // 16 K-tiles
constexpr int UNIT = 16384;                       // 128 x 64 bf16
constexpr int DBUF = 4 * UNIT;                    // 64 KB per buffer

__global__ void __launch_bounds__(512, 2)
snn_gemm_if_8ph(const short* __restrict__ Abf,  // (N*T, DIN) bf16 {0,1}
                const short* __restrict__ Wn,   // (DOUT, DIN) bf16, folded
                const float* __restrict__ bias, const float* __restrict__ gamma,
                const float* __restrict__ beta, const float* __restrict__ rmean,
                const float* __restrict__ rvar, float* __restrict__ out) {
    __shared__ __align__(16) char sm[2 * DBUF];   // 128 KB; potS aliases
    __shared__ float bstepS[BN2];

    const int tid = threadIdx.x;
    // XCD-chunked swizzle: 512 blocks, 64 contiguous works per XCD;
    // 4 consecutive works share an A panel.
    const int work = (blockIdx.x & 7) * 64 + (blockIdx.x >> 3);
    const int oB = (work & 3) * BN2;
    const int rg = work >> 2;                     // A rows rg*256.., samples rg*4..

    if (tid < BN2) {
        int o = oB + tid;
        float r = gamma[o] / sqrtf(rvar[o]);
        bstepS[tid] = ((bias[o] - rmean[o]) * r + beta[o]) * (1.0f / 64.0f);
    }
    // retire bstep loads so vmcnt accounting below is exact
    asm volatile("s_waitcnt vmcnt(0)" ::: "memory");
    __builtin_amdgcn_sched_barrier(0);

    const int lane = tid & 63;
    const int wv   = tid >> 6;                    // 0..7
    const int wr   = wv >> 2;                     // 0..1: M-half (128 rows)
    const int wc   = wv & 3;                      // 0..3: N 64-col band
    const int l15  = lane & 15;
    const int quad = lane >> 4;

    // per-lane ds_read sub-offsets (chunk swizzle c ^= row&7; row&7==lane&7)
    const int D0 = l15 * 128 + ((quad ^ (lane & 7)) * 16);        // ks=0
    const int D1 = l15 * 128 + (((4 + quad) ^ (lane & 7)) * 16);  // ks=1

    // staging: thread covers unit slots tid and tid+512.
    // slot s: row=s>>3, linear chunk s&7 <- global chunk (s&7)^(row&7).
    const int row0 = tid >> 3,         ck0 = (tid & 7) ^ (row0 & 7);
    const int row1 = (512 + tid) >> 3, ck1 = ((512 + tid) & 7) ^ (row1 & 7);
    const int srcOff0 = (row0 * DIN + ck0 * 8) * 2;   // bytes
    const int srcOff1 = (row1 * DIN + ck1 * 8) * 2;

    const char* aU[2] = { (const char*)(Abf + (size_t)rg * BM2 * DIN),
                          (const char*)(Abf + (size_t)(rg * BM2 + 128) * DIN) };
    const char* bU[2] = { (const char*)(Wn + (size_t)oB * DIN),
                          (const char*)(Wn + (size_t)(oB + 128) * DIN) };

    auto STAGE = [&](const char* uPtr, int ktB, int dstB) {
        load_lds_16B(uPtr + srcOff0 + ktB, sm + dstB + tid * 16);
        load_lds_16B(uPtr + srcOff1 + ktB, sm + dstB + 8192 + tid * 16);
    };
    auto LD8 = [&](const char* p) {
        return __builtin_bit_cast(bf16x8, *(const short8v*)p);
    };

    f32x4 acc[8][4] = {};
    bf16x8 af[4][2], bf0[2][2], bf1[2][2];

    // within-buffer read bases for this wave
    const int aBase = wr * UNIT;                          // unit A{wr}
    const int bBase = 2 * UNIT + (wc >> 1) * UNIT + (wc & 1) * 8192;

    // ---- prologue: kt0 (buf0) then kt1 (buf1); land kt0 ----
    STAGE(aU[0], 0, 0);           STAGE(aU[1], 0, UNIT);
    STAGE(bU[0], 0, 2 * UNIT);    STAGE(bU[1], 0, 3 * UNIT);
    STAGE(aU[0], 128, DBUF);      STAGE(aU[1], 128, DBUF + UNIT);
    STAGE(bU[0], 128, DBUF + 2 * UNIT);
    STAGE(bU[1], 128, DBUF + 3 * UNIT);
    asm volatile("s_waitcnt vmcnt(8)" ::: "memory");      // kt0's 8 loads done
    __builtin_amdgcn_sched_barrier(0);
    __builtin_amdgcn_s_barrier();
    __builtin_amdgcn_sched_barrier(0);

    #pragma unroll 1
    for (int g = 0; g < NKT; ++g) {
        const int bufB  = (g & 1) ? DBUF : 0;
        const int obufB = (g & 1) ? 0 : DBUF;             // buf[(g+1)&1]
        const int ktB1  = (g + 1) * 128;                  // A-stage K offset
        const int ktB2  = (g + 2) * 128;                  // B-stage K offset
        const char* pA = sm + bufB + aBase;
        const char* pB = sm + bufB + bBase;
        const bool stA = (g >= 1) && (g <= NKT - 2);      // kt g+1 A units
        const bool stB = (g <= NKT - 3);                  // kt g+2 B units

        // ================= q0: quadrant (mh=0, nh=0) =================
        #pragma unroll
        for (int i = 0; i < 4; i++) {                     // A-mh0: 8 reads
            af[i][0] = LD8(pA + i * 2048 + D0);
            af[i][1] = LD8(pA + i * 2048 + D1);
        }
        #pragma unroll
        for (int j = 0; j < 2; j++) {                     // B-nh0: 4 reads
            bf0[j][0] = LD8(pB + j * 2048 + D0);
            bf0[j][1] = LD8(pB + j * 2048 + D1);
        }
        if (stA) STAGE(aU[0], ktB1, obufB);               // A0(g+1)
        __builtin_amdgcn_s_barrier();
        __builtin_amdgcn_s_setprio(1);
        #pragma unroll
        for (int mi = 0; mi < 4; mi++)
            #pragma unroll
            for (int ni = 0; ni < 2; ni++)
                #pragma unroll
                for (int ks = 0; ks < 2; ks++)
                    acc[mi][ni] = __builtin_amdgcn_mfma_f32_16x16x32_bf16(
                        af[mi][ks], bf0[ni][ks], acc[mi][ni], 0, 0, 0);
        __builtin_amdgcn_s_setprio(0);
        __builtin_amdgcn_s_barrier();

        // ================= q1: quadrant (mh=0, nh=1) =================
        #pragma unroll
        for (int j = 0; j < 2; j++) {                     // B-nh1: 4 reads
            bf1[j][0] = LD8(pB + 4096 + j * 2048 + D0);
            bf1[j][1] = LD8(pB + 4096 + j * 2048 + D1);
        }
        if (stA) STAGE(aU[1], ktB1, obufB + UNIT);        // A1(g+1)
        __builtin_amdgcn_s_barrier();
        __builtin_amdgcn_s_setprio(1);
        #pragma unroll
        for (int mi = 0; mi < 4; mi++)
            #pragma unroll
            for (int ni = 0; ni < 2; ni++)
                #pragma unroll
                for (int ks = 0; ks < 2; ks++)
                    acc[mi][2 + ni] = __builtin_amdgcn_mfma_f32_16x16x32_bf16(
                        af[mi][ks], bf1[ni][ks], acc[mi][2 + ni], 0, 0, 0);
        __builtin_amdgcn_s_setprio(0);
        __builtin_amdgcn_s_barrier();

        // ================= q2: quadrant (mh=1, nh=0) =================
        #pragma unroll
        for (int i = 0; i < 4; i++) {                     // A-mh1: 8 reads
            af[i][0] = LD8(pA + 8192 + i * 2048 + D0);
            af[i][1] = LD8(pA + 8192 + i * 2048 + D1);
        }
        if (stB) STAGE(bU[0], ktB2, bufB + 2 * UNIT);     // B0(g+2)
        __builtin_amdgcn_s_barrier();
        __builtin_amdgcn_s_setprio(1);
        #pragma unroll
        for (int mi = 0; mi < 4; mi++)
            #pragma unroll
            for (int ni = 0; ni < 2; ni++)
                #pragma unroll
                for (int ks = 0; ks < 2; ks++)
                    acc[4 + mi][ni] = __builtin_amdgcn_mfma_f32_16x16x32_bf16(
                        af[mi][ks], bf0[ni][ks], acc[4 + mi][ni], 0, 0, 0);
        __builtin_amdgcn_s_setprio(0);
        __builtin_amdgcn_s_barrier();

        // ================= q3: quadrant (mh=1, nh=1) =================
        if (stB) STAGE(bU[1], ktB2, bufB + 3 * UNIT);     // B1(g+2)
        __builtin_amdgcn_s_barrier();
        __builtin_amdgcn_s_setprio(1);
        #pragma unroll
        for (int mi = 0; mi < 4; mi++)
            #pragma unroll
            for (int ni = 0; ni < 2; ni++)
                #pragma unroll
                for (int ks = 0; ks < 2; ks++)
                    acc[4 + mi][2 + ni] = __builtin_amdgcn_mfma_f32_16x16x32_bf16(
                        af[mi][ks], bf1[ni][ks], acc[4 + mi][2 + ni], 0, 0, 0);
        __builtin_amdgcn_s_setprio(0);
        // ---- once-per-K-tile checkpoint: kt g+1 fully landed ----
        if (g <= NKT - 3) {
            asm volatile("s_waitcnt vmcnt(4)" ::: "memory");
        } else if (g == NKT - 2) {
            asm volatile("s_waitcnt vmcnt(0)" ::: "memory");
        }
        __builtin_amdgcn_sched_barrier(0);
        __builtin_amdgcn_s_barrier();
        __builtin_amdgcn_sched_barrier(0);
    }

    __syncthreads();                              // full drain; potS aliases

    // ---- epilogue (r2-verified): 2 rounds of 2 samples ----
    float* potS = (float*)sm;                     // 128 x 256 fp32 = 128 KB
    #pragma unroll 1
    for (int rd = 0; rd < 2; ++rd) {
        if (wr == rd) {                           // this wave's 128 rows
            #pragma unroll
            for (int mi = 0; mi < 8; mi++)
                #pragma unroll
                for (int ni = 0; ni < 4; ni++)
                    #pragma unroll
                    for (int r = 0; r < 4; r++) {
                        int rowl = mi * 16 + quad * 4 + r;
                        int col  = (wc * 64 + ni * 16 + l15) ^ (quad << 3);
                        potS[rowl * BN2 + col] = acc[mi][ni][r];
                    }
        }
        __syncthreads();
        {
            int sl = tid >> 8;                    // 0..1: sample within round
            int c  = tid & 255;
            int n  = rg * 4 + rd * 2 + sl;
            float pot = 0.f, cnt = 0.f;
            const float bst = bstepS[c];
            float* so = out + (size_t)n * T * DOUT + oB + c;
            for (int tt = 0; tt < T; tt++) {
                pot += potS[(sl * 64 + tt) * BN2 + (c ^ (((tt >> 2) & 3) << 3))] + bst;
                float spk = (pot >= 1.0f) ? 1.0f : 0.0f;
                pot -= spk;
                cnt += spk;
                __builtin_nontemporal_store(spk, so + (size_t)tt * DOUT);
            }
            __builtin_nontemporal_store(
                cnt, out + (size_t)NB * T * DOUT + (size_t)n * DOUT + oB + c);
        }
        __syncthreads();
    }
}

// ===================== fallback (round-2 proven path) =====================

constexpr int BM = 128, BN = 128, BK = 64;
constexpr int LDA_F = 72;
constexpr int A_BYTES_F = BM * LDA_F * 2;
constexpr int SMEM_F = A_BYTES_F + BN * BK * 2;

template <bool PREFOLD>
__global__ void __launch_bounds__(256)
snn_gemm_if(const float* __restrict__ A, const float* __restrict__ W,
            const short* __restrict__ Wn,
            const float* __restrict__ bias, const float* __restrict__ gamma,
            const float* __restrict__ beta, const float* __restrict__ rmean,
            const float* __restrict__ rvar, float* __restrict__ out) {
    __shared__ __align__(16) char smem[SMEM_F];
    __shared__ float ratioS[BN];
    __shared__ float bstepS[BN];
    short* AsS  = (short*)smem;
    short* BsS  = (short*)(smem + A_BYTES_F);
    float* potS = (float*)smem;

    const int tid   = threadIdx.x;
    const int by    = blockIdx.y;
    const int oBase = blockIdx.x * BN;

    if (tid < BN) {
        int o = oBase + tid;
        float r = gamma[o] / sqrtf(rvar[o]);
        ratioS[tid] = r;
        bstepS[tid] = ((bias[o] - rmean[o]) * r + beta[o]) * (1.0f / 64.0f);
    }
    __syncthreads();

    const int lane = tid & 63;
    const int wv   = tid >> 6;
    const int wr   = wv & 1;
    const int wc   = wv >> 1;
    const int l15  = lane & 15;
    const int quad = lane >> 4;

    f32x4 acc[4][4] = {};
    const float* Ab = A + (size_t)by * BM * DIN;

    for (int kb = 0; kb < DIN; kb += BK) {
        float4v av[4][2];
        #pragma unroll
        for (int i = 0; i < 4; i++) {
            int g = i * 256 + tid;
            int r = g >> 3, k8 = g & 7;
            const float4v* p = (const float4v*)(Ab + (size_t)r * DIN + kb + k8 * 8);
            av[i][0] = p[0];
            av[i][1] = p[1];
        }
        float4v bv[4][2];
        if constexpr (!PREFOLD) {
            #pragma unroll
            for (int i = 0; i < 4; i++) {
                int slot = i * 256 + tid;
                int r = slot >> 3, k8 = (slot & 7) ^ (r & 7);
                const float4v* p = (const float4v*)(W + (size_t)(oBase + r) * DIN + kb + k8 * 8);
                bv[i][0] = p[0];
                bv[i][1] = p[1];
            }
        }
        __syncthreads();

        if constexpr (PREFOLD) {
            #pragma unroll
            for (int i = 0; i < 4; i++) {
                int slot = i * 256 + tid;
                int r = slot >> 3, k8 = (slot & 7) ^ (r & 7);
                load_lds_16B(Wn + (size_t)(oBase + r) * DIN + kb + k8 * 8,
                             BsS + (size_t)slot * 8);
            }
        } else {
            #pragma unroll
            for (int i = 0; i < 4; i++) {
                int slot = i * 256 + tid;
                int r = slot >> 3;
                float rt = ratioS[r];
                short8v s;
                #pragma unroll
                for (int j = 0; j < 4; j++) {
                    s[j]     = f2bf_rne(bv[i][0][j] * rt);
                    s[j + 4] = f2bf_rne(bv[i][1][j] * rt);
                }
                *(short8v*)(BsS + (size_t)slot * 8) = s;
            }
        }
        #pragma unroll
        for (int i = 0; i < 4; i++) {
            int g = i * 256 + tid;
            int r = g >> 3, k8 = g & 7;
            short8v s;
            #pragma unroll
            for (int j = 0; j < 4; j++) {
                s[j]     = f2bf_trunc(av[i][0][j]);
                s[j + 4] = f2bf_trunc(av[i][1][j]);
            }
            *(short8v*)(&AsS[r * LDA_F + k8 * 8]) = s;
        }
        __syncthreads();

        #pragma unroll
        for (int ks = 0; ks < 2; ks++) {
            bf16x8 af[4], bfv[4];
            #pragma unroll
            for (int mi = 0; mi < 4; mi++)
                af[mi] = __builtin_bit_cast(bf16x8,
                    *(const short8v*)(&AsS[(wr * 64 + mi * 16 + l15) * LDA_F + ks * 32 + quad * 8]));
            #pragma unroll
            for (int ni = 0; ni < 4; ni++) {
                int row  = wc * 64 + ni * 16 + l15;
                int slot = row * 8 + ((ks * 4 + quad) ^ (l15 & 7));
                bfv[ni] = __builtin_bit_cast(bf16x8, *(const short8v*)(BsS + (size_t)slot * 8));
            }
            #pragma unroll
            for (int mi = 0; mi < 4; mi++)
                #pragma unroll
                for (int ni = 0; ni < 4; ni++)
                    acc[mi][ni] = __builtin_amdgcn_mfma_f32_16x16x32_bf16(
                        af[mi], bfv[ni], acc[mi][ni], 0, 0, 0);
        }
    }

    __syncthreads();

    #pragma unroll 1
    for (int s = 0; s < 2; s++) {
        if (wr == s) {
            #pragma unroll
            for (int mi = 0; mi < 4; mi++)
                #pragma unroll
                for (int ni = 0; ni < 4; ni++)
                    #pragma unroll
                    for (int r = 0; r < 4; r++)
                        potS[(mi * 16 + quad * 4 + r) * BN + wc * 64 + ni * 16 + l15] =
                            acc[mi][ni][r];
        }
        __syncthreads();
        if (tid < BN) {
            int n = by * 2 + s;
            float pot = 0.f, cnt = 0.f;
            const float bst = bstepS[tid];
            float* so = out + (size_t)n * T * DOUT + oBase + tid;
            for (int t = 0; t < T; t++) {
                pot += potS[t * BN + tid] + bst;
                float spk = (pot >= 1.0f) ? 1.0f : 0.0f;
                pot -= spk;
                cnt += spk;
                so[(size_t)t * DOUT] = spk;
            }
            out[(size_t)NB * T * DOUT + (size_t)n * DOUT + oBase + tid] = cnt;
        }
        __syncthreads();
    }
}

extern "C" void kernel_launch(void* const* d_in, const int* in_sizes, int n_in,
                              void* d_out, int out_size, void* d_ws, size_t ws_size,
                              hipStream_t stream) {
    const float* A     = (const float*)d_in[0];
    // d_in[1] (input_features_sc) feeds only the un-returned ANN path — dead.
    const float* W     = (const float*)d_in[2];
    const float* bias  = (const float*)d_in[3];
    const float* gamma = (const float*)d_in[4];
    const float* beta  = (const float*)d_in[5];
    const float* rmean = (const float*)d_in[6];
    const float* rvar  = (const float*)d_in[7];
    float* out = (float*)d_out;

    if (d_ws != nullptr && ws_size >= WS_BF16) {
        short* Abf = (short*)d_ws;
        short* Wn  = (short*)((char*)d_ws + ABF_BYTES);
        prep_fused<<<PREP_A_BLOCKS + PREP_W_BLOCKS, 256, 0, stream>>>(
            A, Abf, W, gamma, rvar, Wn);
        snn_gemm_if_8ph<<<dim3(512), 512, 0, stream>>>(Abf, Wn, bias, gamma,
                                                       beta, rmean, rvar, out);
    } else if (d_ws != nullptr && ws_size >= WN_BYTES) {
        short* Wn = (short*)d_ws;
        fold_w_kernel<<<DOUT * DIN / 4 / 256, 256, 0, stream>>>(W, gamma, rvar, Wn);
        dim3 grid(DOUT / BN, NB / 2);
        snn_gemm_if<true><<<grid, 256, 0, stream>>>(A, W, Wn, bias, gamma, beta,
                                                    rmean, rvar, out);
    } else {
        dim3 grid(DOUT / BN, NB / 2);
        snn_gemm_if<false><<<grid, 256, 0, stream>>>(A, W, nullptr, bias, gamma, beta,
                                                     rmean, rvar, out);
    }
}